// Round 1
// baseline (242.925 us; speedup 1.0000x reference)
//
#include <hip/hip_runtime.h>

#define N_NODES 100000
#define N_EDGES 600000
#define NT1 1563    // k1 node tiles of 64
#define NT2 9375    // k2 edge tiles of 64 (600000 = 9375*64 exactly)
#define LDH 136     // padded row stride (f16 elems), 16B-aligned rows
typedef _Float16 f16x8 __attribute__((ext_vector_type(8)));
typedef __attribute__((ext_vector_type(4))) float f32x4;
typedef __attribute__((ext_vector_type(16))) float f32x16;

__device__ __forceinline__ float elu_f(float v) {
    return v > 0.0f ? v : (__expf(v) - 1.0f);
}

// k1 v2: 32x32x16 MFMA + direct-to-global epilogue.
// Old version bounced the accumulator through LDS (64 scalar ds_writes + 8
// ds_reads + 4 extra barriers per tile) purely to coalesce f16 stores. The
// 32x32 C-fragment (col = lane&31) already gives dense 64B store segments,
// so the bounce and 4 of the 6 per-tile barriers are deleted.
// Wave w covers output cols [w*64, w*64+64): waves 0,1 -> P[:,0:128] (src half),
// waves 2,3 -> P[:,128:256] (tgt half).
extern "C" __global__ __launch_bounds__(256, 3)
void k1_node_linear(const float* __restrict__ x, const float* __restrict__ W1,
                    _Float16* __restrict__ P) {
    __shared__ __align__(16) _Float16 sX[64 * LDH];   // 17.4 KB

    const int t = threadIdx.x;
    const int w = t >> 6, lane = t & 63;
    const int l31 = lane & 31, hi = lane >> 5;
    const int le = t >> 2;        // staging row 0..63
    const int q  = t & 3;         // 32-col chunk 0..3
    const int half = w >> 1;      // which W1 k-half this wave's columns use

    // B frags (32x32x16): col = (w&1)*64 + c*32 + l31 within the half,
    // k = ks*16 + hi*8 + j. 16 frags = 64 VGPR, loaded once per block.
    f16x8 bfw[2][8];
#pragma unroll
    for (int c = 0; c < 2; ++c) {
        const int ncol = (w & 1) * 64 + c * 32 + l31;
#pragma unroll
        for (int ks = 0; ks < 8; ++ks) {
            f16x8 v;
#pragma unroll
            for (int j = 0; j < 8; ++j) {
                int k = half * 128 + ks * 16 + hi * 8 + j;
                v[j] = (_Float16)W1[k * 128 + ncol];
            }
            bfw[c][ks] = v;
        }
    }

    for (int tile = blockIdx.x; tile < NT1; tile += gridDim.x) {
        const int n0 = tile * 64;
        __syncthreads();   // previous tile's A-frag reads of sX done

        // Stage x tile as f16 (single coalesced read of x).
        {
            int n = n0 + le;
#pragma unroll
            for (int i = 0; i < 4; ++i) {
                float4 a0 = make_float4(0.f, 0.f, 0.f, 0.f), a1 = a0;
                if (n < N_NODES) {
                    const float* p = x + (size_t)n * 128 + q * 32 + i * 8;
                    a0 = *(const float4*)p; a1 = *(const float4*)(p + 4);
                }
                f16x8 vh;
                vh[0] = (_Float16)a0.x; vh[1] = (_Float16)a0.y;
                vh[2] = (_Float16)a0.z; vh[3] = (_Float16)a0.w;
                vh[4] = (_Float16)a1.x; vh[5] = (_Float16)a1.y;
                vh[6] = (_Float16)a1.z; vh[7] = (_Float16)a1.w;
                *(f16x8*)(&sX[le * LDH + q * 32 + i * 8]) = vh;
            }
        }
        __syncthreads();

        // MFMA: A row = l31 (+rt*32), k-octet selected by hi. 32 MFMAs/wave.
        f32x16 acc[2][2] = {};
#pragma unroll
        for (int ks = 0; ks < 8; ++ks)
#pragma unroll
            for (int rt = 0; rt < 2; ++rt) {
                f16x8 a = *(const f16x8*)(&sX[(rt * 32 + l31) * LDH + ks * 16 + hi * 8]);
#pragma unroll
                for (int c = 0; c < 2; ++c)
                    acc[rt][c] = __builtin_amdgcn_mfma_f32_32x32x16_f16(
                        a, bfw[c][ks], acc[rt][c], 0, 0, 0);
            }

        // Direct epilogue: C layout col=l31, row=(reg&3)+8*(reg>>2)+4*hi [m74/m101].
        // Each store instr: 32 lanes x 2B contiguous = dense 64B segments.
        if (n0 + 64 <= N_NODES) {
#pragma unroll
            for (int rt = 0; rt < 2; ++rt)
#pragma unroll
                for (int c = 0; c < 2; ++c) {
                    _Float16* pb = P + (size_t)(n0 + rt * 32 + hi * 4) * 256
                                     + w * 64 + c * 32 + l31;
#pragma unroll
                    for (int reg = 0; reg < 16; ++reg) {
                        int roff = (reg & 3) + ((reg >> 2) << 3);
                        pb[(size_t)roff * 256] = (_Float16)acc[rt][c][reg];
                    }
                }
        } else {
#pragma unroll
            for (int rt = 0; rt < 2; ++rt)
#pragma unroll
                for (int c = 0; c < 2; ++c)
#pragma unroll
                    for (int reg = 0; reg < 16; ++reg) {
                        int row = rt * 32 + hi * 4 + (reg & 3) + ((reg >> 2) << 3);
                        int n = n0 + row;
                        if (n < N_NODES)
                            P[(size_t)n * 256 + w * 64 + c * 32 + l31] =
                                (_Float16)acc[rt][c][reg];
                    }
        }
    }
}

// k2: 64-edge tiles, single-barrier software pipeline through double-buffered LDS.
// Change this round: 4 blocks/CU (was 3). LDS 4*37.4KB = 149.5KB <= 160KB,
// VGPR 84 <= 128 cap -> no respill. Kernel is latency-bound on random gathers
// (Occupancy 25%, VALUBusy 45%, HBM 21%) so +33% resident waves is the lever.
extern "C" __global__ __launch_bounds__(256, 4)
void k2_edge_mlp(const _Float16* __restrict__ P, const void* __restrict__ eiv,
                 const float* __restrict__ b1, const float* __restrict__ W2,
                 const float* __restrict__ b2, const float* __restrict__ W3,
                 const float* __restrict__ b3, float* __restrict__ out) {
    __shared__ __align__(16) _Float16 sH[2][64 * LDH];   // 34.8 KB
    __shared__ float sPart[2][4][64];                    // 2 KB
    __shared__ int sFlag;

    const int t = threadIdx.x;
    const int w = t >> 6, lane = t & 63;
    const int ln = lane & 15, kg = lane >> 4;
    const int row = t >> 2;          // staging row 0..63
    const int kc0 = (t & 3) * 4;     // staging k-chunk base (of 16 chunks/row)
    const float b3v = b3[0];
    const int stride = gridDim.x;

    if (t < 64) {
        unsigned v = ((const unsigned*)eiv)[2 * t + 1];
        unsigned long long bm = __ballot(v == 0u);
        if (t == 0) sFlag = (bm == ~0ull) ? 1 : 0;
    }

    f16x8 b1f[4];
#pragma unroll
    for (int i = 0; i < 4; ++i)
#pragma unroll
        for (int j = 0; j < 8; ++j) b1f[i][j] = (_Float16)b1[(kc0 + i) * 8 + j];

    float w3v[2], b2v[2];
#pragma unroll
    for (int c = 0; c < 2; ++c) {
        int col = w * 32 + c * 16 + ln;
        w3v[c] = W3[col]; b2v[c] = b2[col];
    }

    f16x8 bfw[2][4];
#pragma unroll
    for (int c = 0; c < 2; ++c) {
        const int n = w * 32 + c * 16 + ln;
#pragma unroll
        for (int ks = 0; ks < 4; ++ks) {
            f16x8 v;
#pragma unroll
            for (int j = 0; j < 8; ++j) {
                int k = ks * 32 + kg * 8 + j;
                v[j] = (_Float16)W2[k * 128 + n];
            }
            bfw[c][ks] = v;
        }
    }
    __syncthreads();
    const int mode64 = sFlag;

    const int tile0 = blockIdx.x;   // gridDim 1024 <= NT2 always

    int se_nx, ge_nx;
    {
        int e = tile0 * 64 + row;
        if (mode64) {
            se_nx = (int)((const long long*)eiv)[e];
            ge_nx = (int)((const long long*)eiv)[N_EDGES + e];
        } else {
            se_nx = ((const int*)eiv)[e];
            ge_nx = ((const int*)eiv)[N_EDGES + e];
        }
    }
    {
        const _Float16* pa = P + (size_t)se_nx * 256 + kc0 * 8;
        const _Float16* pb = P + (size_t)ge_nx * 256 + 128 + kc0 * 8;
        f16x8 Ga[4], Gb[4];
#pragma unroll
        for (int i = 0; i < 4; ++i) {
            Ga[i] = *(const f16x8*)(pa + i * 8);
            Gb[i] = *(const f16x8*)(pb + i * 8);
        }
#pragma unroll
        for (int i = 0; i < 4; ++i) {
            f16x8 s = Ga[i] + Gb[i] + b1f[i];   // packed f16 adds
            f16x8 vh;
#pragma unroll
            for (int j = 0; j < 8; ++j) {
                _Float16 sv = s[j];
                vh[j] = (sv > (_Float16)0) ? sv
                        : (_Float16)(__expf((float)sv) - 1.0f);
            }
            *(f16x8*)(&sH[0][row * LDH + (kc0 + i) * 8]) = vh;
        }
    }
    {
        int t1 = tile0 + stride;
        int t1c = (t1 < NT2) ? t1 : tile0;
        int e = t1c * 64 + row;
        if (mode64) {
            se_nx = (int)((const long long*)eiv)[e];
            ge_nx = (int)((const long long*)eiv)[N_EDGES + e];
        } else {
            se_nx = ((const int*)eiv)[e];
            ge_nx = ((const int*)eiv)[N_EDGES + e];
        }
    }
    __syncthreads();   // sH[0] ready

    int p = 0;
    int prevE0 = -1;
    for (int tile = tile0; tile < NT2; tile += stride) {
        const int nt = tile + stride;
        const int ntc = (nt < NT2) ? nt : tile;

        // (1) Issue gathers for tile nt.
        const _Float16* pa = P + (size_t)se_nx * 256 + kc0 * 8;
        const _Float16* pb = P + (size_t)ge_nx * 256 + 128 + kc0 * 8;
        f16x8 Ga[4], Gb[4];
#pragma unroll
        for (int i = 0; i < 4; ++i) {
            Ga[i] = *(const f16x8*)(pa + i * 8);
            Gb[i] = *(const f16x8*)(pb + i * 8);
        }

        // (1b) Indices for tile nt+stride.
        {
            int n2 = nt + stride;
            int n2c = (n2 < NT2) ? n2 : ntc;
            int e = n2c * 64 + row;
            if (mode64) {
                se_nx = (int)((const long long*)eiv)[e];
                ge_nx = (int)((const long long*)eiv)[N_EDGES + e];
            } else {
                se_nx = ((const int*)eiv)[e];
                ge_nx = ((const int*)eiv)[N_EDGES + e];
            }
        }

        // (2) Out-write for the previous tile.
        if (prevE0 >= 0 && t < 64)
            out[prevE0 + t] = sPart[p ^ 1][0][t] + sPart[p ^ 1][1][t] +
                              sPart[p ^ 1][2][t] + sPart[p ^ 1][3][t] + b3v;

        // (3) MFMA on sH[p] + fused layer 3 -> sPart[p].
        f32x4 acc[4][2];
#pragma unroll
        for (int rt = 0; rt < 4; ++rt)
#pragma unroll
            for (int c = 0; c < 2; ++c) acc[rt][c] = (f32x4){0.f, 0.f, 0.f, 0.f};

#pragma unroll
        for (int ks = 0; ks < 4; ++ks) {
#pragma unroll
            for (int rt = 0; rt < 4; ++rt) {
                f16x8 a = *(const f16x8*)(&sH[p][(rt * 16 + ln) * LDH + ks * 32 + kg * 8]);
#pragma unroll
                for (int c = 0; c < 2; ++c)
                    acc[rt][c] = __builtin_amdgcn_mfma_f32_16x16x32_f16(a, bfw[c][ks], acc[rt][c], 0, 0, 0);
            }
        }

#pragma unroll
        for (int rt = 0; rt < 4; ++rt) {
            float pr[4] = {0.f, 0.f, 0.f, 0.f};
#pragma unroll
            for (int c = 0; c < 2; ++c) {
#pragma unroll
                for (int reg = 0; reg < 4; ++reg)
                    pr[reg] += elu_f(acc[rt][c][reg] + b2v[c]) * w3v[c];
            }
#pragma unroll
            for (int m = 1; m < 16; m <<= 1)
#pragma unroll
                for (int reg = 0; reg < 4; ++reg) pr[reg] += __shfl_xor(pr[reg], m, 64);
            if (ln == 0) {
#pragma unroll
                for (int reg = 0; reg < 4; ++reg)
                    sPart[p][w][rt * 16 + kg * 4 + reg] = pr[reg];
            }
        }

        // (4) Combine gathered tile nt -> sH[p^1] (packed f16 math).
#pragma unroll
        for (int i = 0; i < 4; ++i) {
            f16x8 s = Ga[i] + Gb[i] + b1f[i];   // v_pk_add_f16
            f16x8 vh;
#pragma unroll
            for (int j = 0; j < 8; ++j) {
                _Float16 sv = s[j];
                vh[j] = (sv > (_Float16)0) ? sv
                        : (_Float16)(__expf((float)sv) - 1.0f);
            }
            *(f16x8*)(&sH[p ^ 1][row * LDH + (kc0 + i) * 8]) = vh;
        }

        prevE0 = tile * 64;
        __syncthreads();   // the ONLY per-tile barrier
        p ^= 1;
    }

    if (prevE0 >= 0 && t < 64)
        out[prevE0 + t] = sPart[p ^ 1][0][t] + sPart[p ^ 1][1][t] +
                          sPart[p ^ 1][2][t] + sPart[p ^ 1][3][t] + b3v;
}

extern "C" void kernel_launch(void* const* d_in, const int* in_sizes, int n_in,
                              void* d_out, int out_size, void* d_ws, size_t ws_size,
                              hipStream_t stream) {
    const float* x  = (const float*)d_in[0];
    const void*  ei = d_in[1];
    const float* W1 = (const float*)d_in[2];
    const float* b1 = (const float*)d_in[3];
    const float* W2 = (const float*)d_in[4];
    const float* b2 = (const float*)d_in[5];
    const float* W3 = (const float*)d_in[6];
    const float* b3 = (const float*)d_in[7];
    float* out = (float*)d_out;

    _Float16* P = (_Float16*)((char*)d_ws + 256);  // 100000*256 f16 = 51.2 MB

    k1_node_linear<<<768, 256, 0, stream>>>(x, W1, P);
    k2_edge_mlp<<<1024, 256, 0, stream>>>(P, ei, b1, W2, b2, W3, b3, out);
}

// Round 2
// 224.576 us; speedup vs baseline: 1.0817x; 1.0817x over previous
//
#include <hip/hip_runtime.h>

#define N_NODES 100000
#define N_EDGES 600000
#define NT1 1563    // k1 node tiles of 64
#define NT2 9375    // k2 edge tiles of 64 (600000 = 9375*64 exactly)
#define LDH 136     // padded row stride (f16 elems), 16B-aligned rows
#define LDO 264     // epilogue bounce row stride (256 cols + pad), 16B-aligned
typedef _Float16 f16x8 __attribute__((ext_vector_type(8)));
typedef _Float16 f16x4 __attribute__((ext_vector_type(4)));
typedef __attribute__((ext_vector_type(4))) float f32x4;

__device__ __forceinline__ float elu_f(float v) {
    return v > 0.0f ? v : (__expf(v) - 1.0f);
}

// k1 v3: all global traffic is FLAT-COALESCED (lane i <-> byte i*16, 1KB dense
// per wave instruction); LDS does all layout shuffling.
//   - v0/v2 staging loads put 64 lanes on 64 distinct 64B lines per instruction
//     (16 rows x 4 chunks at 128B stride) -> TA-serialized scatter, ~0.9 TB/s.
//   - epilogue: ONE bounce through a separate sOut[64][LDO] covering both
//     halves -> 3 barriers/tile (was 6), and P rows leave as dense 512B.
//   - v2's direct 2B scalar stores are gone (they inflated WRITE to 85MB vs
//     51MB payload via partial-line writebacks).
extern "C" __global__ __launch_bounds__(256, 3)
void k1_node_linear(const float* __restrict__ x, const float* __restrict__ W1,
                    _Float16* __restrict__ P) {
    __shared__ __align__(16) _Float16 sX[64 * LDH];    // 17.4 KB staging
    __shared__ __align__(16) _Float16 sOut[64 * LDO];  // 33.8 KB bounce (51.2 KB tot, 3/CU ok)

    const int t = threadIdx.x;
    const int w = t >> 6, lane = t & 63;
    const int ln = lane & 15, kg = lane >> 4;

    // W1 fragments, both halves, this wave's 32-col strip: 64 VGPR, loaded once.
    f16x8 bf[2][2][4];
#pragma unroll
    for (int half = 0; half < 2; ++half)
#pragma unroll
        for (int c = 0; c < 2; ++c) {
            const int n = w * 32 + c * 16 + ln;
#pragma unroll
            for (int ks = 0; ks < 4; ++ks) {
                f16x8 v;
#pragma unroll
                for (int j = 0; j < 8; ++j) {
                    int k = half * 128 + ks * 32 + kg * 8 + j;
                    v[j] = (_Float16)W1[k * 128 + n];
                }
                bf[half][c][ks] = v;
            }
        }

    for (int tile = blockIdx.x; tile < NT1; tile += gridDim.x) {
        const int n0 = tile * 64;

        // Stage x tile: flat-coalesced. Tile = 32KB contiguous; thread t loads
        // float4 at byte t*16 (+4KB strides). 1KB dense per wave instruction.
        {
            const size_t fbase = (size_t)n0 * 128;
#pragma unroll
            for (int i = 0; i < 8; ++i) {
                const int f = t * 4 + i * 1024;       // f32 index in tile
                float4 a = make_float4(0.f, 0.f, 0.f, 0.f);
                if (fbase + (size_t)f < (size_t)N_NODES * 128)
                    a = *(const float4*)(x + fbase + f);
                f16x4 h;
                h[0] = (_Float16)a.x; h[1] = (_Float16)a.y;
                h[2] = (_Float16)a.z; h[3] = (_Float16)a.w;
                *(f16x4*)(&sX[(f >> 7) * LDH + (f & 127)]) = h;
            }
        }
        __syncthreads();   // bar1: sX ready

        // MFMA: identical fragment math to v0 (proven layout).
        f32x4 acc[2][4][2];
#pragma unroll
        for (int half = 0; half < 2; ++half)
#pragma unroll
            for (int rt = 0; rt < 4; ++rt)
#pragma unroll
                for (int c = 0; c < 2; ++c) acc[half][rt][c] = (f32x4){0.f, 0.f, 0.f, 0.f};

#pragma unroll
        for (int ks = 0; ks < 4; ++ks) {
#pragma unroll
            for (int rt = 0; rt < 4; ++rt) {
                f16x8 a = *(const f16x8*)(&sX[(rt * 16 + ln) * LDH + ks * 32 + kg * 8]);
#pragma unroll
                for (int half = 0; half < 2; ++half)
#pragma unroll
                    for (int c = 0; c < 2; ++c)
                        acc[half][rt][c] = __builtin_amdgcn_mfma_f32_16x16x32_f16(
                            a, bf[half][c][ks], acc[half][rt][c], 0, 0, 0);
            }
        }
        __syncthreads();   // bar2: all A-reads of sX done (safe to restage next iter)

        // Single bounce: both halves -> sOut (C-layout [m89/m91]).
#pragma unroll
        for (int half = 0; half < 2; ++half)
#pragma unroll
            for (int rt = 0; rt < 4; ++rt)
#pragma unroll
                for (int c = 0; c < 2; ++c) {
                    const int col = half * 128 + w * 32 + c * 16 + ln;
#pragma unroll
                    for (int reg = 0; reg < 4; ++reg) {
                        const int row = rt * 16 + kg * 4 + reg;
                        sOut[row * LDO + col] = (_Float16)acc[half][rt][c][reg];
                    }
                }
        __syncthreads();   // bar3: sOut ready

        // P store: flat-coalesced. Tile of P = 32KB contiguous f16; thread t
        // stores f16x8 at byte t*16 (+4KB strides). 1KB dense per instruction.
        {
            const size_t ebase = (size_t)n0 * 256;
#pragma unroll
            for (int i = 0; i < 8; ++i) {
                const int e = t * 8 + i * 2048;       // f16 index in tile
                if (n0 + (e >> 8) < N_NODES) {
                    f16x8 v = *(const f16x8*)(&sOut[(e >> 8) * LDO + (e & 255)]);
                    *(f16x8*)(P + ebase + e) = v;
                }
            }
        }
        // no loop-top barrier needed: next staging writes sX (disjoint from
        // sOut); bar1 of the next iter orders it against these sOut reads.
    }
}

// k2: EXACT round-0 revert. 3 blocks/CU, grid 768. Round-1's 4 blocks/CU
// doubled FETCH (141->302MB) by thrashing L2 with +33% concurrent random
// gather streams -> locality-limited, not occupancy-limited.
extern "C" __global__ __launch_bounds__(256, 3)
void k2_edge_mlp(const _Float16* __restrict__ P, const void* __restrict__ eiv,
                 const float* __restrict__ b1, const float* __restrict__ W2,
                 const float* __restrict__ b2, const float* __restrict__ W3,
                 const float* __restrict__ b3, float* __restrict__ out) {
    __shared__ __align__(16) _Float16 sH[2][64 * LDH];   // 34.8 KB
    __shared__ float sPart[2][4][64];                    // 2 KB
    __shared__ int sFlag;

    const int t = threadIdx.x;
    const int w = t >> 6, lane = t & 63;
    const int ln = lane & 15, kg = lane >> 4;
    const int row = t >> 2;          // staging row 0..63
    const int kc0 = (t & 3) * 4;     // staging k-chunk base (of 16 chunks/row)
    const float b3v = b3[0];
    const int stride = gridDim.x;

    if (t < 64) {
        unsigned v = ((const unsigned*)eiv)[2 * t + 1];
        unsigned long long bm = __ballot(v == 0u);
        if (t == 0) sFlag = (bm == ~0ull) ? 1 : 0;
    }

    f16x8 b1f[4];
#pragma unroll
    for (int i = 0; i < 4; ++i)
#pragma unroll
        for (int j = 0; j < 8; ++j) b1f[i][j] = (_Float16)b1[(kc0 + i) * 8 + j];

    float w3v[2], b2v[2];
#pragma unroll
    for (int c = 0; c < 2; ++c) {
        int col = w * 32 + c * 16 + ln;
        w3v[c] = W3[col]; b2v[c] = b2[col];
    }

    f16x8 bfw[2][4];
#pragma unroll
    for (int c = 0; c < 2; ++c) {
        const int n = w * 32 + c * 16 + ln;
#pragma unroll
        for (int ks = 0; ks < 4; ++ks) {
            f16x8 v;
#pragma unroll
            for (int j = 0; j < 8; ++j) {
                int k = ks * 32 + kg * 8 + j;
                v[j] = (_Float16)W2[k * 128 + n];
            }
            bfw[c][ks] = v;
        }
    }
    __syncthreads();
    const int mode64 = sFlag;

    const int tile0 = blockIdx.x;   // 768 <= NT2 always

    int se_nx, ge_nx;
    {
        int e = tile0 * 64 + row;
        if (mode64) {
            se_nx = (int)((const long long*)eiv)[e];
            ge_nx = (int)((const long long*)eiv)[N_EDGES + e];
        } else {
            se_nx = ((const int*)eiv)[e];
            ge_nx = ((const int*)eiv)[N_EDGES + e];
        }
    }
    {
        const _Float16* pa = P + (size_t)se_nx * 256 + kc0 * 8;
        const _Float16* pb = P + (size_t)ge_nx * 256 + 128 + kc0 * 8;
        f16x8 Ga[4], Gb[4];
#pragma unroll
        for (int i = 0; i < 4; ++i) {
            Ga[i] = *(const f16x8*)(pa + i * 8);
            Gb[i] = *(const f16x8*)(pb + i * 8);
        }
#pragma unroll
        for (int i = 0; i < 4; ++i) {
            f16x8 s = Ga[i] + Gb[i] + b1f[i];   // packed f16 adds
            f16x8 vh;
#pragma unroll
            for (int j = 0; j < 8; ++j) {
                _Float16 sv = s[j];
                vh[j] = (sv > (_Float16)0) ? sv
                        : (_Float16)(__expf((float)sv) - 1.0f);
            }
            *(f16x8*)(&sH[0][row * LDH + (kc0 + i) * 8]) = vh;
        }
    }
    {
        int t1 = tile0 + stride;
        int t1c = (t1 < NT2) ? t1 : tile0;
        int e = t1c * 64 + row;
        if (mode64) {
            se_nx = (int)((const long long*)eiv)[e];
            ge_nx = (int)((const long long*)eiv)[N_EDGES + e];
        } else {
            se_nx = ((const int*)eiv)[e];
            ge_nx = ((const int*)eiv)[N_EDGES + e];
        }
    }
    __syncthreads();   // sH[0] ready

    int p = 0;
    int prevE0 = -1;
    for (int tile = tile0; tile < NT2; tile += stride) {
        const int nt = tile + stride;
        const int ntc = (nt < NT2) ? nt : tile;

        // (1) Issue gathers for tile nt.
        const _Float16* pa = P + (size_t)se_nx * 256 + kc0 * 8;
        const _Float16* pb = P + (size_t)ge_nx * 256 + 128 + kc0 * 8;
        f16x8 Ga[4], Gb[4];
#pragma unroll
        for (int i = 0; i < 4; ++i) {
            Ga[i] = *(const f16x8*)(pa + i * 8);
            Gb[i] = *(const f16x8*)(pb + i * 8);
        }

        // (1b) Indices for tile nt+stride.
        {
            int n2 = nt + stride;
            int n2c = (n2 < NT2) ? n2 : ntc;
            int e = n2c * 64 + row;
            if (mode64) {
                se_nx = (int)((const long long*)eiv)[e];
                ge_nx = (int)((const long long*)eiv)[N_EDGES + e];
            } else {
                se_nx = ((const int*)eiv)[e];
                ge_nx = ((const int*)eiv)[N_EDGES + e];
            }
        }

        // (2) Out-write for the previous tile.
        if (prevE0 >= 0 && t < 64)
            out[prevE0 + t] = sPart[p ^ 1][0][t] + sPart[p ^ 1][1][t] +
                              sPart[p ^ 1][2][t] + sPart[p ^ 1][3][t] + b3v;

        // (3) MFMA on sH[p] + fused layer 3 -> sPart[p].
        f32x4 acc[4][2];
#pragma unroll
        for (int rt = 0; rt < 4; ++rt)
#pragma unroll
            for (int c = 0; c < 2; ++c) acc[rt][c] = (f32x4){0.f, 0.f, 0.f, 0.f};

#pragma unroll
        for (int ks = 0; ks < 4; ++ks) {
#pragma unroll
            for (int rt = 0; rt < 4; ++rt) {
                f16x8 a = *(const f16x8*)(&sH[p][(rt * 16 + ln) * LDH + ks * 32 + kg * 8]);
#pragma unroll
                for (int c = 0; c < 2; ++c)
                    acc[rt][c] = __builtin_amdgcn_mfma_f32_16x16x32_f16(a, bfw[c][ks], acc[rt][c], 0, 0, 0);
            }
        }

#pragma unroll
        for (int rt = 0; rt < 4; ++rt) {
            float pr[4] = {0.f, 0.f, 0.f, 0.f};
#pragma unroll
            for (int c = 0; c < 2; ++c) {
#pragma unroll
                for (int reg = 0; reg < 4; ++reg)
                    pr[reg] += elu_f(acc[rt][c][reg] + b2v[c]) * w3v[c];
            }
#pragma unroll
            for (int m = 1; m < 16; m <<= 1)
#pragma unroll
                for (int reg = 0; reg < 4; ++reg) pr[reg] += __shfl_xor(pr[reg], m, 64);
            if (ln == 0) {
#pragma unroll
                for (int reg = 0; reg < 4; ++reg)
                    sPart[p][w][rt * 16 + kg * 4 + reg] = pr[reg];
            }
        }

        // (4) Combine gathered tile nt -> sH[p^1] (packed f16 math).
#pragma unroll
        for (int i = 0; i < 4; ++i) {
            f16x8 s = Ga[i] + Gb[i] + b1f[i];   // v_pk_add_f16
            f16x8 vh;
#pragma unroll
            for (int j = 0; j < 8; ++j) {
                _Float16 sv = s[j];
                vh[j] = (sv > (_Float16)0) ? sv
                        : (_Float16)(__expf((float)sv) - 1.0f);
            }
            *(f16x8*)(&sH[p ^ 1][row * LDH + (kc0 + i) * 8]) = vh;
        }

        prevE0 = tile * 64;
        __syncthreads();   // the ONLY per-tile barrier
        p ^= 1;
    }

    if (prevE0 >= 0 && t < 64)
        out[prevE0 + t] = sPart[p ^ 1][0][t] + sPart[p ^ 1][1][t] +
                          sPart[p ^ 1][2][t] + sPart[p ^ 1][3][t] + b3v;
}

extern "C" void kernel_launch(void* const* d_in, const int* in_sizes, int n_in,
                              void* d_out, int out_size, void* d_ws, size_t ws_size,
                              hipStream_t stream) {
    const float* x  = (const float*)d_in[0];
    const void*  ei = d_in[1];
    const float* W1 = (const float*)d_in[2];
    const float* b1 = (const float*)d_in[3];
    const float* W2 = (const float*)d_in[4];
    const float* b2 = (const float*)d_in[5];
    const float* W3 = (const float*)d_in[6];
    const float* b3 = (const float*)d_in[7];
    float* out = (float*)d_out;

    _Float16* P = (_Float16*)((char*)d_ws + 256);  // 100000*256 f16 = 51.2 MB

    k1_node_linear<<<768, 256, 0, stream>>>(x, W1, P);
    k2_edge_mlp<<<768, 256, 0, stream>>>(P, ei, b1, W2, b2, W3, b3, out);
}

// Round 3
// 207.332 us; speedup vs baseline: 1.1717x; 1.0832x over previous
//
#include <hip/hip_runtime.h>

#define N_NODES 100000
#define N_EDGES 600000
#define NT2 9375    // edge tiles of 64 (600000 = 9375*64 exactly)
#define LDW 264     // LDS row stride (f16): 256 data cols + 8 pad, 16B-aligned
typedef _Float16 f16x8 __attribute__((ext_vector_type(8)));
typedef __attribute__((ext_vector_type(4))) float f32x4;

__device__ __forceinline__ float elu_f(float v) {
    return v > 0.0f ? v : (__expf(v) - 1.0f);
}

// k0: x f32 -> f16 table for k2's gathers. 51.2MB read + 25.6MB write, pure
// streaming. Replaces the entire former k1 (whose 110-140us cost two rounds
// of probing failed to explain): gathering raw x-f16 rows moves the W1 GEMM
// into k2 where the matrix pipe is 91% idle, and HALVES the gather table
// (51.2 -> 25.6MB) so L2 covers 2x more of it.
extern "C" __global__ __launch_bounds__(256)
void k0_convert(const float* __restrict__ x, _Float16* __restrict__ xh) {
    const int step = gridDim.x * blockDim.x;
    for (int c = blockIdx.x * blockDim.x + threadIdx.x; c < (N_NODES * 128) / 8;
         c += step) {
        const float4 a0 = *(const float4*)(x + (size_t)c * 8);
        const float4 a1 = *(const float4*)(x + (size_t)c * 8 + 4);
        f16x8 h;
        h[0] = (_Float16)a0.x; h[1] = (_Float16)a0.y;
        h[2] = (_Float16)a0.z; h[3] = (_Float16)a0.w;
        h[4] = (_Float16)a1.x; h[5] = (_Float16)a1.y;
        h[6] = (_Float16)a1.z; h[7] = (_Float16)a1.w;
        *(f16x8*)(xh + (size_t)c * 8) = h;
    }
}

// k2 fused: per 64-edge tile, gather xh[src],xh[tgt] rows (same logical bytes
// as the old P gather, half the table), layer-1 MFMA vs resident W1 frags
// (f32 accumulate: more accurate than the old packed-f16 half-sum), elu ->
// h1 into LDS, then the unchanged layer-2 + reduce + out pipeline.
// LDS 69.6KB -> 2 blocks/CU; grid 512. Gathers for tile t+1 are issued at
// the top of tile t and held in regs across the whole compute phase.
extern "C" __global__ __launch_bounds__(256, 2)
void k2_edge_mlp(const _Float16* __restrict__ xh, const void* __restrict__ eiv,
                 const float* __restrict__ W1, const float* __restrict__ b1,
                 const float* __restrict__ W2, const float* __restrict__ b2,
                 const float* __restrict__ W3, const float* __restrict__ b3,
                 float* __restrict__ out) {
    __shared__ __align__(16) _Float16 sRaw[2][64 * LDW];  // 2 x 33.8 KB
    __shared__ float sPart[2][4][64];                     // 2 KB
    __shared__ int sFlag;

    const int t = threadIdx.x;
    const int w = t >> 6, lane = t & 63;
    const int ln = lane & 15, kg = lane >> 4;
    const int row_s = t >> 2;        // staging row 0..63
    const int qb = (t & 3) * 32;     // staging 32-col chunk base
    const float b3v = b3[0];
    const int stride = gridDim.x;

    if (t < 64) {
        unsigned v = ((const unsigned*)eiv)[2 * t + 1];
        unsigned long long bm = __ballot(v == 0u);
        if (t == 0) sFlag = (bm == ~0ull) ? 1 : 0;
    }

    // Layer-1 B-frags: both W1 k-halves, this wave's 32-col strip. 64 VGPR.
    f16x8 bf1[2][2][4];
#pragma unroll
    for (int half = 0; half < 2; ++half)
#pragma unroll
        for (int c = 0; c < 2; ++c) {
            const int n = w * 32 + c * 16 + ln;
#pragma unroll
            for (int ks = 0; ks < 4; ++ks) {
                f16x8 v;
#pragma unroll
                for (int j = 0; j < 8; ++j) {
                    int k = half * 128 + ks * 32 + kg * 8 + j;
                    v[j] = (_Float16)W1[k * 128 + n];
                }
                bf1[half][c][ks] = v;
            }
        }

    // Layer-2 B-frags. 32 VGPR.
    f16x8 bf2[2][4];
#pragma unroll
    for (int c = 0; c < 2; ++c) {
        const int n = w * 32 + c * 16 + ln;
#pragma unroll
        for (int ks = 0; ks < 4; ++ks) {
            f16x8 v;
#pragma unroll
            for (int j = 0; j < 8; ++j) {
                int k = ks * 32 + kg * 8 + j;
                v[j] = (_Float16)W2[k * 128 + n];
            }
            bf2[c][ks] = v;
        }
    }

    float b1v[2], b2v[2], w3v[2];
#pragma unroll
    for (int c = 0; c < 2; ++c) {
        int col = w * 32 + c * 16 + ln;
        b1v[c] = b1[col]; b2v[c] = b2[col]; w3v[c] = W3[col];
    }

    __syncthreads();
    const int mode64 = sFlag;
    const int tile0 = blockIdx.x;   // 512 <= NT2 always

    int se_nx, ge_nx;
    // Prologue: stage tile0 into sRaw[0].
    {
        int e = tile0 * 64 + row_s;
        int se, ge;
        if (mode64) {
            se = (int)((const long long*)eiv)[e];
            ge = (int)((const long long*)eiv)[N_EDGES + e];
        } else {
            se = ((const int*)eiv)[e];
            ge = ((const int*)eiv)[N_EDGES + e];
        }
        const _Float16* pa = xh + (size_t)se * 128 + qb;
        const _Float16* pb = xh + (size_t)ge * 128 + qb;
#pragma unroll
        for (int i = 0; i < 4; ++i) {
            f16x8 ga = *(const f16x8*)(pa + i * 8);
            f16x8 gb = *(const f16x8*)(pb + i * 8);
            *(f16x8*)(&sRaw[0][row_s * LDW + qb + i * 8]) = ga;
            *(f16x8*)(&sRaw[0][row_s * LDW + 128 + qb + i * 8]) = gb;
        }
    }
    {
        int t1 = tile0 + stride;
        int t1c = (t1 < NT2) ? t1 : tile0;
        int e = t1c * 64 + row_s;
        if (mode64) {
            se_nx = (int)((const long long*)eiv)[e];
            ge_nx = (int)((const long long*)eiv)[N_EDGES + e];
        } else {
            se_nx = ((const int*)eiv)[e];
            ge_nx = ((const int*)eiv)[N_EDGES + e];
        }
    }
    __syncthreads();   // sRaw[0] ready

    int p = 0;
    int prevE0 = -1;
    for (int tile = tile0; tile < NT2; tile += stride) {
        const int nt = tile + stride;
        const int ntc = (nt < NT2) ? nt : tile;

        // (1) Issue gathers for tile nt; regs stay live across the compute
        //     phase so HBM/LLC latency hides under MFMA+VALU.
        const _Float16* pa = xh + (size_t)se_nx * 128 + qb;
        const _Float16* pb = xh + (size_t)ge_nx * 128 + qb;
        f16x8 Ga[4], Gb[4];
#pragma unroll
        for (int i = 0; i < 4; ++i) {
            Ga[i] = *(const f16x8*)(pa + i * 8);
            Gb[i] = *(const f16x8*)(pb + i * 8);
        }

        // (1b) Indices for tile nt+stride.
        {
            int n2 = nt + stride;
            int n2c = (n2 < NT2) ? n2 : ntc;
            int e = n2c * 64 + row_s;
            if (mode64) {
                se_nx = (int)((const long long*)eiv)[e];
                ge_nx = (int)((const long long*)eiv)[N_EDGES + e];
            } else {
                se_nx = ((const int*)eiv)[e];
                ge_nx = ((const int*)eiv)[N_EDGES + e];
            }
        }

        // (2) Out-write for the previous tile.
        if (prevE0 >= 0 && t < 64)
            out[prevE0 + t] = sPart[p ^ 1][0][t] + sPart[p ^ 1][1][t] +
                              sPart[p ^ 1][2][t] + sPart[p ^ 1][3][t] + b3v;

        // (3) Layer 1: h1 = src.W1a + tgt.W1b, f32 accumulate.
        f32x4 acc1[4][2];
#pragma unroll
        for (int rt = 0; rt < 4; ++rt)
#pragma unroll
            for (int c = 0; c < 2; ++c) acc1[rt][c] = (f32x4){0.f, 0.f, 0.f, 0.f};

#pragma unroll
        for (int ks = 0; ks < 4; ++ks) {
#pragma unroll
            for (int rt = 0; rt < 4; ++rt) {
                f16x8 a_s = *(const f16x8*)(&sRaw[p][(rt * 16 + ln) * LDW + ks * 32 + kg * 8]);
                f16x8 a_t = *(const f16x8*)(&sRaw[p][(rt * 16 + ln) * LDW + 128 + ks * 32 + kg * 8]);
#pragma unroll
                for (int c = 0; c < 2; ++c) {
                    acc1[rt][c] = __builtin_amdgcn_mfma_f32_16x16x32_f16(
                        a_s, bf1[0][c][ks], acc1[rt][c], 0, 0, 0);
                    acc1[rt][c] = __builtin_amdgcn_mfma_f32_16x16x32_f16(
                        a_t, bf1[1][c][ks], acc1[rt][c], 0, 0, 0);
                }
            }
        }
        __syncthreads();   // B1: all layer-1 A-reads of sRaw[p] done

        // (4) elu -> h1 (f16) into sRaw[p] cols 0:128 (C-layout [m89/m91]).
#pragma unroll
        for (int rt = 0; rt < 4; ++rt)
#pragma unroll
            for (int c = 0; c < 2; ++c) {
                const int col = w * 32 + c * 16 + ln;
#pragma unroll
                for (int reg = 0; reg < 4; ++reg) {
                    const int row = rt * 16 + kg * 4 + reg;
                    sRaw[p][row * LDW + col] =
                        (_Float16)elu_f(acc1[rt][c][reg] + b1v[c]);
                }
            }
        __syncthreads();   // B2: h1 ready

        // (5) Layer 2 + fused layer 3 reduce -> sPart[p].
        f32x4 acc2[4][2];
#pragma unroll
        for (int rt = 0; rt < 4; ++rt)
#pragma unroll
            for (int c = 0; c < 2; ++c) acc2[rt][c] = (f32x4){0.f, 0.f, 0.f, 0.f};

#pragma unroll
        for (int ks = 0; ks < 4; ++ks) {
#pragma unroll
            for (int rt = 0; rt < 4; ++rt) {
                f16x8 a = *(const f16x8*)(&sRaw[p][(rt * 16 + ln) * LDW + ks * 32 + kg * 8]);
#pragma unroll
                for (int c = 0; c < 2; ++c)
                    acc2[rt][c] = __builtin_amdgcn_mfma_f32_16x16x32_f16(
                        a, bf2[c][ks], acc2[rt][c], 0, 0, 0);
            }
        }

#pragma unroll
        for (int rt = 0; rt < 4; ++rt) {
            float pr[4] = {0.f, 0.f, 0.f, 0.f};
#pragma unroll
            for (int c = 0; c < 2; ++c) {
#pragma unroll
                for (int reg = 0; reg < 4; ++reg)
                    pr[reg] += elu_f(acc2[rt][c][reg] + b2v[c]) * w3v[c];
            }
#pragma unroll
            for (int m = 1; m < 16; m <<= 1)
#pragma unroll
                for (int reg = 0; reg < 4; ++reg) pr[reg] += __shfl_xor(pr[reg], m, 64);
            if (ln == 0) {
#pragma unroll
                for (int reg = 0; reg < 4; ++reg)
                    sPart[p][w][rt * 16 + kg * 4 + reg] = pr[reg];
            }
        }

        // (6) Stage gathered tile nt -> sRaw[p^1].
#pragma unroll
        for (int i = 0; i < 4; ++i) {
            *(f16x8*)(&sRaw[p ^ 1][row_s * LDW + qb + i * 8]) = Ga[i];
            *(f16x8*)(&sRaw[p ^ 1][row_s * LDW + 128 + qb + i * 8]) = Gb[i];
        }

        prevE0 = tile * 64;
        __syncthreads();   // B3: sRaw[p^1] + sPart[p] ready
        p ^= 1;
    }

    if (prevE0 >= 0 && t < 64)
        out[prevE0 + t] = sPart[p ^ 1][0][t] + sPart[p ^ 1][1][t] +
                          sPart[p ^ 1][2][t] + sPart[p ^ 1][3][t] + b3v;
}

extern "C" void kernel_launch(void* const* d_in, const int* in_sizes, int n_in,
                              void* d_out, int out_size, void* d_ws, size_t ws_size,
                              hipStream_t stream) {
    const float* x  = (const float*)d_in[0];
    const void*  ei = d_in[1];
    const float* W1 = (const float*)d_in[2];
    const float* b1 = (const float*)d_in[3];
    const float* W2 = (const float*)d_in[4];
    const float* b2 = (const float*)d_in[5];
    const float* W3 = (const float*)d_in[6];
    const float* b3 = (const float*)d_in[7];
    float* out = (float*)d_out;

    _Float16* xh = (_Float16*)((char*)d_ws + 256);  // 100000*128 f16 = 25.6 MB

    k0_convert<<<2048, 256, 0, stream>>>(x, xh);
    k2_edge_mlp<<<512, 256, 0, stream>>>(xh, ei, W1, b1, W2, b2, W3, b3, out);
}